// Round 1
// baseline (145.202 us; speedup 1.0000x reference)
//
#include <hip/hip_runtime.h>

typedef __bf16 bf16x8 __attribute__((ext_vector_type(8)));
typedef float  f32x4  __attribute__((ext_vector_type(4)));

constexpr int HID = 64;

// Layout facts used (gfx950 mfma_f32_16x16x32_bf16):
//   A-frag: lane l holds A[m = l&15][k = (l>>4)*8 + j], j=0..7 contiguous
//   B-frag: lane l holds B[k = (l>>4)*8 + j][n = l&15]
//   C/D   : lane l reg i holds D[m = (l>>4)*4 + i][n = l&15]   (m89/m91 verified)
//
// We compute transposed: D[c][row] = W^T (A) @ enc^T (B).
// k-permutation pi(32*kk2 + 8g + j) = 32*kk2 + 16*(j>>2) + 4g + (j&3) applied to
// W2/W3 rows makes the layer-(n+1) B-frag equal to the layer-n accumulators
// re-packed in-lane: frag[kk2][j] = relu(acc[2*kk2 + (j>>2)][j&3]).

__global__ __launch_bounds__(256, 2)
void cond_net_kernel(const float* __restrict__ pos, const float* __restrict__ wi,
                     const float* __restrict__ rough,
                     const float* __restrict__ W1, const float* __restrict__ b1,
                     const float* __restrict__ W2, const float* __restrict__ b2,
                     const float* __restrict__ W3, const float* __restrict__ b3,
                     const float* __restrict__ centers,
                     float* __restrict__ out)
{
    __shared__ bf16x8 w1lds[28 * 64];   // [kk*4+mt][lane] fragment-order, 28 KiB

    const int tid = threadIdx.x;
    const int l  = tid & 63;
    const int wv = tid >> 6;       // wave 0..3
    const int g  = l >> 4;
    const int r  = l & 15;

    // ---- stage W1 A-fragments into LDS in per-lane fragment order ----
    for (int u = tid; u < 28 * 64; u += 256) {
        const int fr = u >> 6;          // kk*4 + mt
        const int ll = u & 63;
        const int kk = fr >> 2, mt = fr & 3;
        const int gg = ll >> 4, rr = ll & 15;
        bf16x8 v;
#pragma unroll
        for (int j = 0; j < 8; ++j)
            v[j] = (__bf16)W1[(32 * kk + 8 * gg + j) * HID + 16 * mt + rr];
        w1lds[u] = v;
    }

    // ---- per-lane register fragments for W2, W3 (k-permuted) ----
    bf16x8 w2f[4][2], w3f[4][2];
#pragma unroll
    for (int mt = 0; mt < 4; ++mt)
#pragma unroll
        for (int kk2 = 0; kk2 < 2; ++kk2) {
            bf16x8 v2, v3;
#pragma unroll
            for (int j = 0; j < 8; ++j) {
                const int k = 32 * kk2 + 16 * (j >> 2) + 4 * g + (j & 3);
                v2[j] = (__bf16)W2[k * HID + 16 * mt + r];
                v3[j] = (__bf16)W3[k * HID + 16 * mt + r];
            }
            w2f[mt][kk2] = v2;
            w3f[mt][kk2] = v3;
        }

    // ---- biases (accumulator init), per-lane ----
    f32x4 b1v[4], b2v[4], b3v[4];
#pragma unroll
    for (int mt = 0; mt < 4; ++mt) {
        b1v[mt] = *(const f32x4*)(b1 + 16 * mt + 4 * g);
        b2v[mt] = *(const f32x4*)(b2 + 16 * mt + 4 * g);
        b3v[mt] = *(const f32x4*)(b3 + 16 * mt + 4 * g);
    }

    // enc(x, bin) = exp(-0.5*((x-c)/sigma)^2), sigma=1/32
    //            = exp2(-(K1*(x-c))^2), K1 = sqrt(512*log2 e) = 27.178297
    const float K1 = 27.178297f;
    float c1j[8];
#pragma unroll
    for (int j = 0; j < 8; ++j) c1j[j] = -K1 * centers[8 * g + j];

    __syncthreads();

    const int block_base = blockIdx.x * 512;
    for (int it = 0; it < 8; ++it) {
        __syncthreads();   // keeps the 28 W1 ds_reads per-iteration (no LICM hoist)
        const int row = block_base + it * 64 + wv * 16 + r;

        float xs[7];
        xs[0] = pos[row * 3 + 0]; xs[1] = pos[row * 3 + 1]; xs[2] = pos[row * 3 + 2];
        xs[3] = wi[row * 3 + 0];  xs[4] = wi[row * 3 + 1];  xs[5] = wi[row * 3 + 2];
        xs[6] = rough[row];
#pragma unroll
        for (int d = 0; d < 7; ++d) xs[d] = fminf(fmaxf(xs[d], 0.0f), 1.0f);

        // ---- layer 1: D1[c1][row] = W1^T @ enc^T + b1 ----
        f32x4 acc1[4];
#pragma unroll
        for (int mt = 0; mt < 4; ++mt) acc1[mt] = b1v[mt];

#pragma unroll
        for (int kk = 0; kk < 7; ++kk) {
            bf16x8 ef;
#pragma unroll
            for (int j = 0; j < 8; ++j) {
                const float d = fmaf(K1, xs[kk], c1j[j]);
                ef[j] = (__bf16)exp2f(-(d * d));
            }
#pragma unroll
            for (int mt = 0; mt < 4; ++mt)
                acc1[mt] = __builtin_amdgcn_mfma_f32_16x16x32_bf16(
                    w1lds[(kk * 4 + mt) * 64 + l], ef, acc1[mt], 0, 0, 0);
        }

        // ---- relu + repack h1 as B-frags (in-lane, via pi) ----
        bf16x8 h1f[2];
#pragma unroll
        for (int kk2 = 0; kk2 < 2; ++kk2) {
            bf16x8 v;
#pragma unroll
            for (int j = 0; j < 8; ++j) {
                const float hv = acc1[2 * kk2 + (j >> 2)][j & 3];
                v[j] = (__bf16)fmaxf(hv, 0.0f);
            }
            h1f[kk2] = v;
        }

        // ---- layer 2 ----
        f32x4 acc2[4];
#pragma unroll
        for (int mt = 0; mt < 4; ++mt) acc2[mt] = b2v[mt];
#pragma unroll
        for (int kk2 = 0; kk2 < 2; ++kk2)
#pragma unroll
            for (int mt = 0; mt < 4; ++mt)
                acc2[mt] = __builtin_amdgcn_mfma_f32_16x16x32_bf16(
                    w2f[mt][kk2], h1f[kk2], acc2[mt], 0, 0, 0);

        bf16x8 h2f[2];
#pragma unroll
        for (int kk2 = 0; kk2 < 2; ++kk2) {
            bf16x8 v;
#pragma unroll
            for (int j = 0; j < 8; ++j) {
                const float hv = acc2[2 * kk2 + (j >> 2)][j & 3];
                v[j] = (__bf16)fmaxf(hv, 0.0f);
            }
            h2f[kk2] = v;
        }

        // ---- layer 3 (no relu) ----
        f32x4 acc3[4];
#pragma unroll
        for (int mt = 0; mt < 4; ++mt) acc3[mt] = b3v[mt];
#pragma unroll
        for (int kk2 = 0; kk2 < 2; ++kk2)
#pragma unroll
            for (int mt = 0; mt < 4; ++mt)
                acc3[mt] = __builtin_amdgcn_mfma_f32_16x16x32_bf16(
                    w3f[mt][kk2], h2f[kk2], acc3[mt], 0, 0, 0);

        // ---- store: out[row][c3], c3 = 16*mt + 4*g + i  -> float4 ----
#pragma unroll
        for (int mt = 0; mt < 4; ++mt)
            *(f32x4*)(out + (size_t)row * 64 + 16 * mt + 4 * g) = acc3[mt];
    }
}

extern "C" void kernel_launch(void* const* d_in, const int* in_sizes, int n_in,
                              void* d_out, int out_size, void* d_ws, size_t ws_size,
                              hipStream_t stream) {
    const float* pos     = (const float*)d_in[0];
    const float* wi      = (const float*)d_in[1];
    const float* rough   = (const float*)d_in[2];
    const float* W1      = (const float*)d_in[3];
    const float* b1      = (const float*)d_in[4];
    const float* W2      = (const float*)d_in[5];
    const float* b2      = (const float*)d_in[6];
    const float* W3      = (const float*)d_in[7];
    const float* b3      = (const float*)d_in[8];
    const float* centers = (const float*)d_in[9];
    float* out = (float*)d_out;

    const int n = in_sizes[0] / 3;          // 1048576 rows
    const int blocks = n / 512;             // 512 rows per block
    hipLaunchKernelGGL(cond_net_kernel, dim3(blocks), dim3(256), 0, stream,
                       pos, wi, rough, W1, b1, W2, b2, W3, b3, centers, out);
}

// Round 2
// 128.590 us; speedup vs baseline: 1.1292x; 1.1292x over previous
//
#include <hip/hip_runtime.h>

typedef __bf16 bf16x8 __attribute__((ext_vector_type(8)));
typedef float  f32x4  __attribute__((ext_vector_type(4)));

constexpr int HID = 64;
constexpr float K1   = 27.178297f;        // sqrt(512 * log2(e)); enc = exp2(-(K1*(x-c))^2)
constexpr float STEP = -K1 / 31.0f;       // centers[i] = i/31

// MFMA 16x16x32 bf16 layouts (verified m89/m91):
//   A-frag: lane l holds A[m=l&15][k=(l>>4)*8+j]
//   B-frag: lane l holds B[k=(l>>4)*8+j][n=l&15]
//   C/D  : lane l reg i holds D[m=(l>>4)*4+i][n=l&15]
// Transposed compute: D[c][row] = W^T @ enc^T. k-permutation
// pi(32kk2+8g+j) = 32kk2+16(j>>2)+4g+(j&3) on W2/W3 rows makes each layer's
// B-frag equal to the previous layer's accumulators repacked in-lane.

// ws layout (bf16x8 units): [0,28*64) W1 frags [kk*4+mt][lane]
//                           [28*64,36*64) W2 frags [mt*2+kk2][lane]
//                           [36*64,44*64) W3 frags [mt*2+kk2][lane]
__global__ void prep_kernel(const float* __restrict__ W1,
                            const float* __restrict__ W2,
                            const float* __restrict__ W3,
                            bf16x8* __restrict__ ws)
{
    const int f = blockIdx.x;
    const int l = threadIdx.x;
    const int g = l >> 4, r = l & 15;
    bf16x8 v;
    if (f < 28) {
        const int kk = f >> 2, mt = f & 3;
#pragma unroll
        for (int j = 0; j < 8; ++j)
            v[j] = (__bf16)W1[(32 * kk + 8 * g + j) * HID + 16 * mt + r];
    } else {
        const float* W = (f < 36) ? W2 : W3;
        const int fi = (f < 36) ? (f - 28) : (f - 36);
        const int mt = fi >> 1, kk2 = fi & 1;
#pragma unroll
        for (int j = 0; j < 8; ++j) {
            const int k = 32 * kk2 + 16 * (j >> 2) + 4 * g + (j & 3);
            v[j] = (__bf16)W[k * HID + 16 * mt + r];
        }
    }
    ws[f * 64 + l] = v;
}

__device__ __forceinline__ void mlp_tail(const f32x4* acc1, const bf16x8* w2f,
                                         const bf16x8* w3f, const f32x4* b2v,
                                         const f32x4* b3v,
                                         float* __restrict__ out, int row, int g)
{
    bf16x8 h1f[2];
#pragma unroll
    for (int kk2 = 0; kk2 < 2; ++kk2) {
        bf16x8 v;
#pragma unroll
        for (int j = 0; j < 8; ++j)
            v[j] = (__bf16)fmaxf(acc1[2 * kk2 + (j >> 2)][j & 3], 0.0f);
        h1f[kk2] = v;
    }
    f32x4 acc2[4];
#pragma unroll
    for (int mt = 0; mt < 4; ++mt) acc2[mt] = b2v[mt];
#pragma unroll
    for (int kk2 = 0; kk2 < 2; ++kk2)
#pragma unroll
        for (int mt = 0; mt < 4; ++mt)
            acc2[mt] = __builtin_amdgcn_mfma_f32_16x16x32_bf16(
                w2f[mt * 2 + kk2], h1f[kk2], acc2[mt], 0, 0, 0);

    bf16x8 h2f[2];
#pragma unroll
    for (int kk2 = 0; kk2 < 2; ++kk2) {
        bf16x8 v;
#pragma unroll
        for (int j = 0; j < 8; ++j)
            v[j] = (__bf16)fmaxf(acc2[2 * kk2 + (j >> 2)][j & 3], 0.0f);
        h2f[kk2] = v;
    }
    f32x4 acc3[4];
#pragma unroll
    for (int mt = 0; mt < 4; ++mt) acc3[mt] = b3v[mt];
#pragma unroll
    for (int kk2 = 0; kk2 < 2; ++kk2)
#pragma unroll
        for (int mt = 0; mt < 4; ++mt)
            acc3[mt] = __builtin_amdgcn_mfma_f32_16x16x32_bf16(
                w3f[mt * 2 + kk2], h2f[kk2], acc3[mt], 0, 0, 0);
#pragma unroll
    for (int mt = 0; mt < 4; ++mt)
        *(f32x4*)(out + (size_t)row * 64 + 16 * mt + 4 * g) = acc3[mt];
}

__global__ __launch_bounds__(256, 3)
void cond_net_kernel(const float* __restrict__ pos, const float* __restrict__ wi,
                     const float* __restrict__ rough,
                     const float* __restrict__ b1, const float* __restrict__ b2,
                     const float* __restrict__ b3,
                     const bf16x8* __restrict__ ws,
                     float* __restrict__ out)
{
    __shared__ bf16x8 w1lds[28 * 64];   // 28 KiB, per-lane fragment order

    const int tid = threadIdx.x;
    const int l = tid & 63, wv = tid >> 6, g = l >> 4, r = l & 15;

    // stage W1 frags: wave wv covers frags [wv*7, wv*7+7), 16B/lane, linear LDS
#pragma unroll
    for (int i = 0; i < 7; ++i) {
        const int fr = wv * 7 + i;
        __builtin_amdgcn_global_load_lds(
            (const __attribute__((address_space(1))) void*)(ws + fr * 64 + l),
            (__attribute__((address_space(3))) void*)(w1lds + fr * 64),
            16, 0, 0);
    }

    // W2/W3 fragments: coalesced dwordx4 loads
    bf16x8 w2f[8], w3f[8];
#pragma unroll
    for (int i = 0; i < 8; ++i) w2f[i] = ws[(28 + i) * 64 + l];
#pragma unroll
    for (int i = 0; i < 8; ++i) w3f[i] = ws[(36 + i) * 64 + l];

    f32x4 b1v[4], b2v[4], b3v[4];
#pragma unroll
    for (int mt = 0; mt < 4; ++mt) {
        b1v[mt] = *(const f32x4*)(b1 + 16 * mt + 4 * g);
        b2v[mt] = *(const f32x4*)(b2 + 16 * mt + 4 * g);
        b3v[mt] = *(const f32x4*)(b3 + 16 * mt + 4 * g);
    }

    const float base_g = STEP * (float)(8 * g);

    __syncthreads();   // drains global_load_lds (vmcnt) + barrier

    unsigned int ldsoff = 0;
    const int block_base = blockIdx.x * 512;

#pragma unroll 1
    for (int it = 0; it < 4; ++it) {
        asm volatile("" : "+v"(ldsoff));          // keep ds_reads per-iteration
        const char* lb = (const char*)w1lds + ldsoff + l * 16;

        const int row0 = block_base + it * 128 + wv * 32 + r;
        const int row1 = row0 + 16;

        float xa[7], xb[7];
        xa[0] = pos[row0 * 3 + 0]; xa[1] = pos[row0 * 3 + 1]; xa[2] = pos[row0 * 3 + 2];
        xa[3] = wi[row0 * 3 + 0];  xa[4] = wi[row0 * 3 + 1];  xa[5] = wi[row0 * 3 + 2];
        xa[6] = rough[row0];
        xb[0] = pos[row1 * 3 + 0]; xb[1] = pos[row1 * 3 + 1]; xb[2] = pos[row1 * 3 + 2];
        xb[3] = wi[row1 * 3 + 0];  xb[4] = wi[row1 * 3 + 1];  xb[5] = wi[row1 * 3 + 2];
        xb[6] = rough[row1];
#pragma unroll
        for (int d = 0; d < 7; ++d) {
            xa[d] = fminf(fmaxf(xa[d], 0.0f), 1.0f);
            xb[d] = fminf(fmaxf(xb[d], 0.0f), 1.0f);
        }

        f32x4 accA[4], accB[4];
#pragma unroll
        for (int mt = 0; mt < 4; ++mt) { accA[mt] = b1v[mt]; accB[mt] = b1v[mt]; }

#pragma unroll
        for (int kk = 0; kk < 7; ++kk) {
            const float A0 = fmaf(K1, xa[kk], base_g);
            const float A1 = fmaf(K1, xb[kk], base_g);
            bf16x8 e0, e1;
#pragma unroll
            for (int j = 0; j < 8; ++j) {
                const float d0 = A0 + (float)j * STEP;
                const float d1 = A1 + (float)j * STEP;
                e0[j] = (__bf16)__builtin_amdgcn_exp2f(-(d0 * d0));
                e1[j] = (__bf16)__builtin_amdgcn_exp2f(-(d1 * d1));
            }
#pragma unroll
            for (int mt = 0; mt < 4; ++mt) {
                const bf16x8 wf = *(const bf16x8*)(lb + (kk * 4 + mt) * 1024);
                accA[mt] = __builtin_amdgcn_mfma_f32_16x16x32_bf16(wf, e0, accA[mt], 0, 0, 0);
                accB[mt] = __builtin_amdgcn_mfma_f32_16x16x32_bf16(wf, e1, accB[mt], 0, 0, 0);
            }
        }

        mlp_tail(accA, w2f, w3f, b2v, b3v, out, row0, g);
        mlp_tail(accB, w2f, w3f, b2v, b3v, out, row1, g);
    }
}

extern "C" void kernel_launch(void* const* d_in, const int* in_sizes, int n_in,
                              void* d_out, int out_size, void* d_ws, size_t ws_size,
                              hipStream_t stream) {
    const float* pos     = (const float*)d_in[0];
    const float* wi      = (const float*)d_in[1];
    const float* rough   = (const float*)d_in[2];
    const float* W1      = (const float*)d_in[3];
    const float* b1      = (const float*)d_in[4];
    const float* W2      = (const float*)d_in[5];
    const float* b2      = (const float*)d_in[6];
    const float* W3      = (const float*)d_in[7];
    const float* b3      = (const float*)d_in[8];
    float* out = (float*)d_out;

    bf16x8* ws = (bf16x8*)d_ws;

    const int n = in_sizes[0] / 3;          // 1048576 rows
    hipLaunchKernelGGL(prep_kernel, dim3(44), dim3(64), 0, stream, W1, W2, W3, ws);
    hipLaunchKernelGGL(cond_net_kernel, dim3(n / 512), dim3(256), 0, stream,
                       pos, wi, rough, b1, b2, b3, (const bf16x8*)ws, out);
}

// Round 3
// 85.233 us; speedup vs baseline: 1.7036x; 1.5087x over previous
//
#include <hip/hip_runtime.h>

typedef __bf16 bf16x8 __attribute__((ext_vector_type(8)));
typedef float  f32x4  __attribute__((ext_vector_type(4)));

constexpr int HID = 64;
constexpr float K1   = 27.178297f;        // sqrt(512 * log2(e)); enc = exp2(-(K1*(x-c))^2)
constexpr float STEP = -K1 / 31.0f;       // centers[i] = i/31

// MFMA 16x16x32 bf16 layouts (verified m89/m91):
//   A-frag: lane l holds A[m=l&15][k=(l>>4)*8+j]
//   B-frag: lane l holds B[k=(l>>4)*8+j][n=l&15]
//   C/D  : lane l reg i holds D[m=(l>>4)*4+i][n=l&15]
// Transposed compute: D[c][row] = W^T @ enc^T. k-permutation
// pi(32kk2+8g+j) = 32kk2+16(j>>2)+4g+(j&3) on W2/W3 rows makes each layer's
// B-frag equal to the previous layer's accumulators repacked in-lane.

// ws layout (bf16x8 units): frag f in [0,28): W1 [kk*4+mt];
// f in [28,36): W2 [mt*2+kk2]; f in [36,44): W3 [mt*2+kk2]. 64 lanes each.
__global__ void prep_kernel(const float* __restrict__ W1,
                            const float* __restrict__ W2,
                            const float* __restrict__ W3,
                            bf16x8* __restrict__ ws)
{
    const int f = blockIdx.x;
    const int l = threadIdx.x;
    const int g = l >> 4, r = l & 15;
    bf16x8 v;
    if (f < 28) {
        const int kk = f >> 2, mt = f & 3;
#pragma unroll
        for (int j = 0; j < 8; ++j)
            v[j] = (__bf16)W1[(32 * kk + 8 * g + j) * HID + 16 * mt + r];
    } else {
        const float* W = (f < 36) ? W2 : W3;
        const int fi = (f < 36) ? (f - 28) : (f - 36);
        const int mt = fi >> 1, kk2 = fi & 1;
#pragma unroll
        for (int j = 0; j < 8; ++j) {
            const int k = 32 * kk2 + 16 * (j >> 2) + 4 * g + (j & 3);
            v[j] = (__bf16)W[k * HID + 16 * mt + r];
        }
    }
    ws[f * 64 + l] = v;
}

__device__ __forceinline__ void load_x(const float* __restrict__ pos,
                                       const float* __restrict__ wi,
                                       const float* __restrict__ rough,
                                       int row, float* x)
{
    x[0] = pos[row * 3 + 0]; x[1] = pos[row * 3 + 1]; x[2] = pos[row * 3 + 2];
    x[3] = wi[row * 3 + 0];  x[4] = wi[row * 3 + 1];  x[5] = wi[row * 3 + 2];
    x[6] = rough[row];
}

__device__ __forceinline__ void mlp_tail(const f32x4* acc1, const char* lb,
                                         const f32x4* b2v, const f32x4* b3v,
                                         float* __restrict__ out, int row, int g)
{
    bf16x8 h1f[2];
#pragma unroll
    for (int kk2 = 0; kk2 < 2; ++kk2) {
        bf16x8 v;
#pragma unroll
        for (int j = 0; j < 8; ++j)
            v[j] = (__bf16)fmaxf(acc1[2 * kk2 + (j >> 2)][j & 3], 0.0f);
        h1f[kk2] = v;
    }
    f32x4 acc2[4];
#pragma unroll
    for (int mt = 0; mt < 4; ++mt) acc2[mt] = b2v[mt];
#pragma unroll
    for (int kk2 = 0; kk2 < 2; ++kk2)
#pragma unroll
        for (int mt = 0; mt < 4; ++mt) {
            const bf16x8 wf = *(const bf16x8*)(lb + (28 + mt * 2 + kk2) * 1024);
            acc2[mt] = __builtin_amdgcn_mfma_f32_16x16x32_bf16(wf, h1f[kk2], acc2[mt], 0, 0, 0);
        }

    bf16x8 h2f[2];
#pragma unroll
    for (int kk2 = 0; kk2 < 2; ++kk2) {
        bf16x8 v;
#pragma unroll
        for (int j = 0; j < 8; ++j)
            v[j] = (__bf16)fmaxf(acc2[2 * kk2 + (j >> 2)][j & 3], 0.0f);
        h2f[kk2] = v;
    }
    f32x4 acc3[4];
#pragma unroll
    for (int mt = 0; mt < 4; ++mt) acc3[mt] = b3v[mt];
#pragma unroll
    for (int kk2 = 0; kk2 < 2; ++kk2)
#pragma unroll
        for (int mt = 0; mt < 4; ++mt) {
            const bf16x8 wf = *(const bf16x8*)(lb + (36 + mt * 2 + kk2) * 1024);
            acc3[mt] = __builtin_amdgcn_mfma_f32_16x16x32_bf16(wf, h2f[kk2], acc3[mt], 0, 0, 0);
        }
#pragma unroll
    for (int mt = 0; mt < 4; ++mt)
        __builtin_nontemporal_store(acc3[mt],
            (f32x4*)(out + (size_t)row * 64 + 16 * mt + 4 * g));
}

__global__ __launch_bounds__(512, 4)
void cond_net_kernel(const float* __restrict__ pos, const float* __restrict__ wi,
                     const float* __restrict__ rough,
                     const float* __restrict__ b1, const float* __restrict__ b2,
                     const float* __restrict__ b3,
                     const bf16x8* __restrict__ ws,
                     float* __restrict__ out)
{
    __shared__ bf16x8 wlds[44 * 64];   // 44 KiB: all weight fragments, lane-linear

    const int tid = threadIdx.x;
    const int l = tid & 63, wv = tid >> 6, g = l >> 4, r = l & 15;

    // stage all 44 fragments via async global->LDS, 1 KiB per call, linear
    for (int fr = wv; fr < 44; fr += 8)
        __builtin_amdgcn_global_load_lds(
            (const __attribute__((address_space(1))) void*)(ws + fr * 64 + l),
            (__attribute__((address_space(3))) void*)(wlds + fr * 64),
            16, 0, 0);

    f32x4 b1v[4], b2v[4], b3v[4];
#pragma unroll
    for (int mt = 0; mt < 4; ++mt) {
        b1v[mt] = *(const f32x4*)(b1 + 16 * mt + 4 * g);
        b2v[mt] = *(const f32x4*)(b2 + 16 * mt + 4 * g);
        b3v[mt] = *(const f32x4*)(b3 + 16 * mt + 4 * g);
    }

    const float base_g = STEP * (float)(8 * g);
    const int rbase = blockIdx.x * 1024 + wv * 32 + r;

    // iter-0 inputs, in-register
    float xc[14];
    load_x(pos, wi, rough, rbase, xc);
    load_x(pos, wi, rough, rbase + 16, xc + 7);

    __syncthreads();   // drains global_load_lds + barrier

    unsigned int ldsoff = 0;
#pragma unroll 1
    for (int it = 0; it < 4; ++it) {
        asm volatile("" : "+v"(ldsoff));          // defeat LICM on LDS reads
        const char* lb = (const char*)wlds + ldsoff + l * 16;

        // prefetch next iteration's inputs (awaited only at the rotate below)
        float xn[14];
        const int nrow = rbase + (it < 3 ? (it + 1) * 256 : 768);
        load_x(pos, wi, rough, nrow, xn);
        load_x(pos, wi, rough, nrow + 16, xn + 7);

        float Aa[7], Ab[7];
#pragma unroll
        for (int d = 0; d < 7; ++d) {
            Aa[d] = fmaf(K1, fminf(fmaxf(xc[d], 0.0f), 1.0f), base_g);
            Ab[d] = fmaf(K1, fminf(fmaxf(xc[7 + d], 0.0f), 1.0f), base_g);
        }

        f32x4 accA[4], accB[4];
#pragma unroll
        for (int mt = 0; mt < 4; ++mt) { accA[mt] = b1v[mt]; accB[mt] = b1v[mt]; }

#pragma unroll
        for (int kk = 0; kk < 7; ++kk) {
            bf16x8 e0, e1;
#pragma unroll
            for (int j = 0; j < 8; ++j) {
                const float d0 = Aa[kk] + (float)j * STEP;
                const float d1 = Ab[kk] + (float)j * STEP;
                e0[j] = (__bf16)__builtin_amdgcn_exp2f(-(d0 * d0));
                e1[j] = (__bf16)__builtin_amdgcn_exp2f(-(d1 * d1));
            }
#pragma unroll
            for (int mt = 0; mt < 4; ++mt) {
                const bf16x8 wf = *(const bf16x8*)(lb + (kk * 4 + mt) * 1024);
                accA[mt] = __builtin_amdgcn_mfma_f32_16x16x32_bf16(wf, e0, accA[mt], 0, 0, 0);
                accB[mt] = __builtin_amdgcn_mfma_f32_16x16x32_bf16(wf, e1, accB[mt], 0, 0, 0);
            }
        }

        const int row0 = rbase + it * 256;
        mlp_tail(accA, lb, b2v, b3v, out, row0, g);
        mlp_tail(accB, lb, b2v, b3v, out, row0 + 16, g);

#pragma unroll
        for (int q = 0; q < 14; ++q) xc[q] = xn[q];
    }
}

extern "C" void kernel_launch(void* const* d_in, const int* in_sizes, int n_in,
                              void* d_out, int out_size, void* d_ws, size_t ws_size,
                              hipStream_t stream) {
    const float* pos     = (const float*)d_in[0];
    const float* wi      = (const float*)d_in[1];
    const float* rough   = (const float*)d_in[2];
    const float* W1      = (const float*)d_in[3];
    const float* b1      = (const float*)d_in[4];
    const float* W2      = (const float*)d_in[5];
    const float* b2      = (const float*)d_in[6];
    const float* W3      = (const float*)d_in[7];
    const float* b3      = (const float*)d_in[8];
    float* out = (float*)d_out;

    bf16x8* ws = (bf16x8*)d_ws;

    const int n = in_sizes[0] / 3;          // 1048576 rows
    hipLaunchKernelGGL(prep_kernel, dim3(44), dim3(64), 0, stream, W1, W2, W3, ws);
    hipLaunchKernelGGL(cond_net_kernel, dim3(n / 1024), dim3(512), 0, stream,
                       pos, wi, rough, b1, b2, b3, (const bf16x8*)ws, out);
}